// Round 8
// baseline (223.102 us; speedup 1.0000x reference)
//
#include <hip/hip_runtime.h>
#include <cstddef>
#include <cstdint>

// GPT-style attention block on MI355X (gfx950), bf16-MFMA.
//   x:[B,N,NX] f32, c_attn_w:[NX,3NX] f32, c_attn_b, c_proj_w:[NX,NX], c_proj_b
//   outputs: a:[B,N,NX] f32, present:[2,B,H,N,hd] f32  (k then v)
// mask input (d_in[5]) ignored: causal mask applied analytically.
#define NX_ 1024
#define NH_ 16
#define HD_ 64
#define B_  2
#define N_  2048
#define M_  (B_ * N_)   // 4096

typedef __attribute__((ext_vector_type(8))) short bf16x8;   // 8 bf16 (4 VGPR)
typedef __attribute__((ext_vector_type(4))) float f32x4;

// fp32 -> bf16 round-to-nearest-even (cold paths)
__device__ __forceinline__ unsigned short f2bf(float f) {
    union { float f; unsigned u; } v; v.f = f;
    return (unsigned short)((v.u + 0x7FFFu + ((v.u >> 16) & 1u)) >> 16);
}
__device__ __forceinline__ unsigned pk2bf(float a, float b) {
    return (unsigned)f2bf(a) | ((unsigned)f2bf(b) << 16);
}
// hot-path pack: round-half-up + v_perm byte select (3 VALU ops)
__device__ __forceinline__ unsigned pkrnd(float a, float b) {
    union { float f; unsigned u; } ua, ub; ua.f = a; ub.f = b;
    return __builtin_amdgcn_perm(ub.u + 0x8000u, ua.u + 0x8000u, 0x07060302u);
}
// bare v_exp_f32 (2^x), bypasses libm fixup; flushes to 0 for very negative x
__device__ __forceinline__ float exp2_hw(float x) {
    float r;
    asm("v_exp_f32 %0, %1" : "=v"(r) : "v"(x));
    return r;
}

// async global->LDS, 16B per lane; LDS dest = wave-uniform base + lane*16
__device__ __forceinline__ void gload_lds16(const void* g, void* l) {
    __builtin_amdgcn_global_load_lds(
        (const __attribute__((address_space(1))) unsigned int*)g,
        (__attribute__((address_space(3))) unsigned int*)l, 16, 0, 0);
}

// ---------------------------------------------------------------------------
// Fused pre-pass (one launch): bid<2048: x f32->bf16; then wqkv / wproj
// f32 -> bf16 TRANSPOSED ([ncols][1024]) via 32x32 LDS tiles.
__global__ __launch_bounds__(256)
void pre_pass(const float* __restrict__ x, unsigned short* __restrict__ xb,
              const float* __restrict__ wqkv, unsigned short* __restrict__ wqkv_t,
              const float* __restrict__ wpr, unsigned short* __restrict__ wproj_t)
{
    const int bid = blockIdx.x, t = threadIdx.x;
    if (bid < 2048) {
        const size_t i = ((size_t)bid * 256 + t) * 8;
        const float4 a = *(const float4*)(x + i);
        const float4 b = *(const float4*)(x + i + 4);
        uint4 o;
        o.x = pk2bf(a.x, a.y); o.y = pk2bf(a.z, a.w);
        o.z = pk2bf(b.x, b.y); o.w = pk2bf(b.z, b.w);
        *(uint4*)(xb + i) = o;
        return;
    }
    __shared__ unsigned short tile[32][40];
    const float* W; unsigned short* Wt; int ncols, n0, k0;
    if (bid < 2048 + 3072) {
        const int b2 = bid - 2048;
        W = wqkv; Wt = wqkv_t; ncols = 3072; n0 = (b2 % 96) * 32; k0 = (b2 / 96) * 32;
    } else {
        const int b3 = bid - 5120;
        W = wpr; Wt = wproj_t; ncols = 1024; n0 = (b3 & 31) * 32; k0 = (b3 >> 5) * 32;
    }
    const int r = t >> 3, c4 = (t & 7) * 4;
    const float4 v = *(const float4*)(W + (size_t)(k0 + r) * ncols + n0 + c4);
    tile[r][c4 + 0] = f2bf(v.x); tile[r][c4 + 1] = f2bf(v.y);
    tile[r][c4 + 2] = f2bf(v.z); tile[r][c4 + 3] = f2bf(v.w);
    __syncthreads();
    uint2 o;
    o.x = (unsigned)tile[c4 + 0][r] | ((unsigned)tile[c4 + 1][r] << 16);
    o.y = (unsigned)tile[c4 + 2][r] | ((unsigned)tile[c4 + 3][r] << 16);
    *(uint2*)(Wt + (size_t)(n0 + r) * 1024 + k0 + c4) = o;
}

// ---------------------------------------------------------------------------
// bf16 GEMM (r6-verified 2-buffer loop): out = A[M,1024] @ Wt[NOUT,1024]^T + bias.
// BM=BN=128, BK=32, 4 waves (2x2), 64x64/wave, dbuf LDS, global_load_lds
// staging with pre-swizzled global source, r6 bijective XCD swizzle.
// MODE 0 (qkv): scatter epilogue -> q_bf (scaled), pk+k_bf, pv+v_bf (ALL
//   row-major [bh][n][d]; v transpose moved into attn's LDS commit).
// MODE 2 (proj, split-K=2): grid doubled; each half does K=512 and
//   atomicAdds into o_f (pre-zeroed via hipMemsetAsync); bias added by half 0.
// Bank-conflict counter note: ~3.1M/dispatch is structural gload_lds DMA
// serialization (8 cyc/instr), NOT read conflicts - benign, do not chase.
template<int NOUT, int MODE, int GX>
__global__ __launch_bounds__(256, 3)
void gemm_mfma(const unsigned short* __restrict__ Ab, const unsigned short* __restrict__ Wt,
               const float* __restrict__ bias,
               float* __restrict__ o_pk, float* __restrict__ o_pv,
               unsigned short* __restrict__ o_q, unsigned short* __restrict__ o_k,
               unsigned short* __restrict__ o_vb, float* __restrict__ o_f)
{
    __shared__ __align__(16) unsigned short As[2][128 * 32];
    __shared__ __align__(16) unsigned short Bs[2][128 * 32];
    const int t = threadIdx.x, l = t & 63;
    const int g = l >> 4, q15 = l & 15;
    const int w = t >> 6, wm = w >> 1, wn = w & 1;

    int m0, j0, kofs, nks;
    if (MODE == 2) {   // split-K=2: bid 0..255 half0, 256..511 half1
        const int ks = (int)blockIdx.x >> 8;
        const int inner = (int)blockIdx.x & 255;
        const int swz = (inner & 7) * 32 + (inner >> 3);
        m0 = (swz >> 3) * 128; j0 = (swz & 7) * 128;
        kofs = ks * 512; nks = 16;
    } else {
        constexpr int nwg = GX * 32;
        const int swz = ((int)blockIdx.x & 7) * (nwg / 8) + ((int)blockIdx.x >> 3);
        m0 = (swz / GX) * 128; j0 = (swz % GX) * 128;
        kofs = 0; nks = 32;
    }

    f32x4 acc[4][4];
#pragma unroll
    for (int ii = 0; ii < 4; ii++)
#pragma unroll
        for (int jj = 0; jj < 4; jj++) { acc[ii][jj][0]=0.f; acc[ii][jj][1]=0.f; acc[ii][jj][2]=0.f; acc[ii][jj][3]=0.f; }

    const int srow[2] = { (w * 2 + 0) * 16 + (l >> 2), (w * 2 + 1) * 16 + (l >> 2) };
    const int kct0 = ((l & 3) ^ (srow[0] & 3) ^ ((srow[0] >> 2) & 3)) & 3;
    const int kct1 = ((l & 3) ^ (srow[1] & 3) ^ ((srow[1] >> 2) & 3)) & 3;

#define STAGE(BUF, K0)                                                          \
    do {                                                                        \
        gload_lds16(Ab + (size_t)(m0 + srow[0]) * 1024 + (K0) + kct0 * 8,       \
                    &As[BUF][(w * 2 + 0) * 64 * 8]);                            \
        gload_lds16(Ab + (size_t)(m0 + srow[1]) * 1024 + (K0) + kct1 * 8,       \
                    &As[BUF][(w * 2 + 1) * 64 * 8]);                            \
        gload_lds16(Wt + (size_t)(j0 + srow[0]) * 1024 + (K0) + kct0 * 8,       \
                    &Bs[BUF][(w * 2 + 0) * 64 * 8]);                            \
        gload_lds16(Wt + (size_t)(j0 + srow[1]) * 1024 + (K0) + kct1 * 8,       \
                    &Bs[BUF][(w * 2 + 1) * 64 * 8]);                            \
    } while (0)

    STAGE(0, kofs);
    __syncthreads();

    for (int kk = 0; kk < nks; ++kk) {
        const int buf = kk & 1;
        if (kk + 1 < nks) STAGE(buf ^ 1, kofs + (kk + 1) * 32);

        bf16x8 af[4], bfv[4];
#pragma unroll
        for (int mt = 0; mt < 4; mt++) {
            const int m = wm * 64 + mt * 16 + q15;
            af[mt] = *(const bf16x8*)&As[buf][m * 32 + ((g ^ (m & 3) ^ ((m >> 2) & 3)) & 3) * 8];
        }
#pragma unroll
        for (int nt = 0; nt < 4; nt++) {
            const int n = wn * 64 + nt * 16 + q15;
            bfv[nt] = *(const bf16x8*)&Bs[buf][n * 32 + ((g ^ (n & 3) ^ ((n >> 2) & 3)) & 3) * 8];
        }
#pragma unroll
        for (int mt = 0; mt < 4; mt++)
#pragma unroll
            for (int nt = 0; nt < 4; nt++)
                acc[mt][nt] = __builtin_amdgcn_mfma_f32_16x16x32_bf16(af[mt], bfv[nt], acc[mt][nt], 0, 0, 0);

        __syncthreads();
    }

#pragma unroll
    for (int nt = 0; nt < 4; nt++) {
        const int ncol = wn * 64 + nt * 16 + q15;
        const int jc = j0 + ncol;
        const float bz = (MODE == 2 && kofs != 0) ? 0.f : bias[jc];
        const int sec = jc >> 10, jl = jc & 1023, hh = jl >> 6, dd = jl & 63;
#pragma unroll
        for (int mt = 0; mt < 4; mt++) {
#pragma unroll
            for (int r = 0; r < 4; r++) {
                const int m = m0 + wm * 64 + mt * 16 + g * 4 + r;
                const float val = acc[mt][nt][r] + bz;
                if (MODE == 2) {
                    atomicAdd(&o_f[(size_t)m * NOUT + jc], val);
                } else {
                    const int bb = m >> 11, nn = m & 2047;
                    const int bhh = bb * NH_ + hh;
                    const size_t idx = ((size_t)bhh * N_ + nn) * HD_ + dd;
                    if (sec == 0)      o_q[idx] = f2bf(val * 0.18033688f); // 1/8 * log2(e)
                    else if (sec == 1) { o_pk[idx] = val; o_k[idx] = f2bf(val); }
                    else               { o_pv[idx] = val; o_vb[idx] = f2bf(val); }
                }
            }
        }
    }
#undef STAGE
}

// ---------------------------------------------------------------------------
// Flash attention, bf16 MFMA, fixed-max softmax. QBLK=128 (8 waves x 16 rows).
// Swapped QK^T (S^T = K.Q^T) -> lane-local P; PV as O^T = V^T.P.
// V is now read ROW-MAJOR ([bh][n][d], coalesced 16B/lane) and transposed
// during the LDS commit via 8 ds_write_b16/thread (2-way banks = free).
// Resulting Vt layout is bit-identical to r6's (slot (n>>3)^(d&7), elem n&7),
// so the swizzled PV fragment reads are unchanged.
__global__ __launch_bounds__(512, 2)
void attn_mfma(const unsigned short* __restrict__ q_bf,
               const unsigned short* __restrict__ k_bf,
               const unsigned short* __restrict__ v_bf,
               unsigned short* __restrict__ a_pre)
{
    __shared__ __align__(16) unsigned short Ks[2][64 * 64];
    __shared__ __align__(16) unsigned short Vt[2][64 * 64];
    __shared__ __align__(16) unsigned short Ps[128 * 64];

    const int t = threadIdx.x, l = t & 63, w = t >> 6;   // w: 0..7
    const int g = l >> 4, q15 = l & 15;

    const int bid = (int)blockIdx.x;
    const int x = bid & 7, r = bid >> 3;                 // r: 0..63
    const int bh = x * 4 + (r & 3);
    const int j = r >> 2;                                // 0..15
    const int qt = (j < 8) ? (15 - j) : (j - 8);
    const int b = bh >> 4, h = bh & 15;

    const unsigned short* kb = k_bf + (size_t)bh * N_ * HD_;
    const unsigned short* vb = v_bf + (size_t)bh * N_ * HD_;

    const int qrow = w * 16 + q15;                       // 0..127
    const int qg = qt * 128 + qrow;                      // global q row
    const unsigned short* qp = q_bf + ((size_t)bh * N_ + qg) * HD_ + g * 8;
    const bf16x8 qf0 = *(const bf16x8*)(qp);
    const bf16x8 qf1 = *(const bf16x8*)(qp + 32);

    // staging: K: thread -> row sr (n), slot s8. V: thread -> n = t&63, d0 = (t>>6)*8
    const int sr = t >> 3, s8 = t & 7;
    const int vn = t & 63, vd0 = (t >> 6) * 8;
    uint4 stgK, stgV;

#define ISSUE(KT)                                                               \
    do {                                                                        \
        stgK = *(const uint4*)(kb + ((size_t)((KT) * 64 + sr)) * HD_ + s8 * 8); \
        stgV = *(const uint4*)(vb + ((size_t)((KT) * 64 + vn)) * HD_ + vd0);    \
    } while (0)

#define COMMIT(BUF)                                                            \
    do {                                                                       \
        *(uint4*)&Ks[BUF][sr * 64 + ((s8 ^ (sr & 7)) & 7) * 8] = stgK;         \
        const unsigned* vu = (const unsigned*)&stgV;                           \
        _Pragma("unroll")                                                      \
        for (int jj = 0; jj < 8; jj++) {                                       \
            const unsigned short e =                                           \
                (unsigned short)(vu[jj >> 1] >> ((jj & 1) * 16));              \
            const int vd = vd0 + jj;                                           \
            Vt[BUF][vd * 64 + ((((vn >> 3) ^ (vd & 7)) & 7) * 8 + (vn & 7))] = e; \
        }                                                                      \
    } while (0)

    ISSUE(0); COMMIT(0);
    __syncthreads();

    float l_i = 0.f;
    f32x4 oacc[4];
#pragma unroll
    for (int i = 0; i < 4; i++) { oacc[i][0]=0.f; oacc[i][1]=0.f; oacc[i][2]=0.f; oacc[i][3]=0.f; }

    int cur = 0;
    char* const prow = (char*)Ps + qrow * 128;
    const int psw = (qrow & 7) << 4;
    const int ktmax = 2 * qt + 1;

    for (int kt = 0; kt <= ktmax; kt++) {
        const bool more = (kt < ktmax);
        if (more) ISSUE(kt + 1);                  // T14: issue next tile early

        // ---- S^T = K . Q^T
        f32x4 sacc[4];
#pragma unroll
        for (int i = 0; i < 4; i++) { sacc[i][0]=0.f; sacc[i][1]=0.f; sacc[i][2]=0.f; sacc[i][3]=0.f; }
        __builtin_amdgcn_s_setprio(1);
#pragma unroll
        for (int kt4 = 0; kt4 < 4; kt4++) {
            const int row = kt4 * 16 + q15;
            const bf16x8 kf0 = *(const bf16x8*)&Ks[cur][row * 64 + ((g ^ (row & 7)) & 7) * 8];
            sacc[kt4] = __builtin_amdgcn_mfma_f32_16x16x32_bf16(kf0, qf0, sacc[kt4], 0, 0, 0);
            const bf16x8 kf1 = *(const bf16x8*)&Ks[cur][row * 64 + (((g + 4) ^ (row & 7)) & 7) * 8];
            sacc[kt4] = __builtin_amdgcn_mfma_f32_16x16x32_bf16(kf1, qf1, sacc[kt4], 0, 0, 0);
        }
        __builtin_amdgcn_s_setprio(0);

        // ---- P = exp2(S), per-thread partial sum, bf16 pack into private Ps rows
        float pe[16];
        if (kt >= 2 * qt) {   // diagonal region: mask global kc > global q
#pragma unroll
            for (int kt4 = 0; kt4 < 4; kt4++)
#pragma unroll
                for (int rr = 0; rr < 4; rr++) {
                    const int kcg = kt * 64 + kt4 * 16 + g * 4 + rr;
                    const float s = (kcg > qg) ? -1.0e30f : sacc[kt4][rr];
                    pe[kt4 * 4 + rr] = exp2_hw(s);
                }
        } else {
#pragma unroll
            for (int kt4 = 0; kt4 < 4; kt4++)
#pragma unroll
                for (int rr = 0; rr < 4; rr++) pe[kt4 * 4 + rr] = exp2_hw(sacc[kt4][rr]);
        }
        {   // tree-sum of the 16 partials (depth 4)
            float s8v[8];
#pragma unroll
            for (int i = 0; i < 8; i++) s8v[i] = pe[2 * i] + pe[2 * i + 1];
            const float s0 = (s8v[0] + s8v[1]) + (s8v[2] + s8v[3]);
            const float s1 = (s8v[4] + s8v[5]) + (s8v[6] + s8v[7]);
            l_i += s0 + s1;
        }
#pragma unroll
        for (int kt4 = 0; kt4 < 4; kt4++) {
            uint2 w2;
            w2.x = pkrnd(pe[kt4 * 4 + 0], pe[kt4 * 4 + 1]);
            w2.y = pkrnd(pe[kt4 * 4 + 2], pe[kt4 * 4 + 3]);
            *(uint2*)(prow + ((kt4 * 32 + g * 8) ^ psw)) = w2;
        }

        // ---- O^T += V^T . P
        {
            const bf16x8 pf0 = *(const bf16x8*)(prow + ((g * 16) ^ psw));
            const bf16x8 pf1 = *(const bf16x8*)(prow + (((g + 4) * 16) ^ psw));
            __builtin_amdgcn_s_setprio(1);
#pragma unroll
            for (int dt = 0; dt < 4; dt++) {
                const int vrow = dt * 16 + q15;
                const bf16x8 vf = *(const bf16x8*)&Vt[cur][vrow * 64 + ((g ^ (vrow & 7)) & 7) * 8];
                oacc[dt] = __builtin_amdgcn_mfma_f32_16x16x32_bf16(vf, pf0, oacc[dt], 0, 0, 0);
            }
#pragma unroll
            for (int dt = 0; dt < 4; dt++) {
                const int vrow = dt * 16 + q15;
                const bf16x8 vf = *(const bf16x8*)&Vt[cur][vrow * 64 + (((g + 4) ^ (vrow & 7)) & 7) * 8];
                oacc[dt] = __builtin_amdgcn_mfma_f32_16x16x32_bf16(vf, pf1, oacc[dt], 0, 0, 0);
            }
            __builtin_amdgcn_s_setprio(0);
        }

        if (more) COMMIT(cur ^ 1);                // write next tile late
        __syncthreads();
        cur ^= 1;
    }

    // deferred cross-lane l reduce (lanes l, l^16, l^32 share the q-column)
    float lt = l_i;
    lt += __shfl_xor(lt, 16);
    lt += __shfl_xor(lt, 32);
    const float inv = 1.0f / lt;

    unsigned short* ap2 = a_pre + ((size_t)(b * N_ + qg)) * NX_ + h * 64;
#pragma unroll
    for (int dt = 0; dt < 4; dt++) {
#pragma unroll
        for (int j2 = 0; j2 < 2; j2++) {
            const int d = dt * 16 + g * 4 + j2 * 2;
            *(unsigned*)(ap2 + d) = pkrnd(oacc[dt][j2 * 2] * inv, oacc[dt][j2 * 2 + 1] * inv);
        }
    }
#undef ISSUE
#undef COMMIT
}

// ---------------------------------------------------------------------------
extern "C" void kernel_launch(void* const* d_in, const int* in_sizes, int n_in,
                              void* d_out, int out_size, void* d_ws, size_t ws_size,
                              hipStream_t stream)
{
    (void)in_sizes; (void)n_in; (void)out_size; (void)ws_size;
    const float* x    = (const float*)d_in[0];
    const float* wqkv = (const float*)d_in[1];
    const float* bqkv = (const float*)d_in[2];
    const float* wpr  = (const float*)d_in[3];
    const float* bpr  = (const float*)d_in[4];
    // d_in[5] (mask) ignored: causal mask applied analytically.

    float* out   = (float*)d_out;
    float* a_out = out;                                  // [B,N,NX] f32
    float* pk    = out + (size_t)M_ * NX_;               // present[0]: k [B,H,N,hd]
    float* pv    = pk + (size_t)B_ * NH_ * N_ * HD_;     // present[1]: v

    // workspace (40 MB): bf16 x / q / k / v (all row-major) / transposed weights.
    // a_pre aliases xb: xb fully consumed by qkv GEMM before attn writes.
    const size_t SEG = (size_t)M_ * NX_;                 // 4M elems
    unsigned short* xb      = (unsigned short*)d_ws;     // [4096][1024]
    unsigned short* q_bf    = xb + SEG;                  // [bh][n][d]
    unsigned short* k_bf    = q_bf + SEG;                // [bh][n][d]
    unsigned short* v_bf    = k_bf + SEG;                // [bh][n][d]
    unsigned short* wqkv_t  = v_bf + SEG;                // [3072][1024]
    unsigned short* wproj_t = wqkv_t + (size_t)3 * NX_ * NX_;  // [1024][1024]
    unsigned short* a_pre   = xb;                        // alias (see above)

    // zero a_out up front (proj accumulates atomically); graph-capture-legal
    hipMemsetAsync(a_out, 0, (size_t)M_ * NX_ * sizeof(float), stream);

    pre_pass<<<2048 + 3072 + 1024, 256, 0, stream>>>(x, xb, wqkv, wqkv_t, wpr, wproj_t);

    gemm_mfma<3 * NX_, 0, 24><<<768, 256, 0, stream>>>(
        xb, wqkv_t, bqkv, pk, pv, q_bf, k_bf, v_bf, nullptr);
    attn_mfma<<<512, 512, 0, stream>>>(q_bf, k_bf, v_bf, a_pre);
    gemm_mfma<NX_, 2, 8><<<512, 256, 0, stream>>>(
        a_pre, wproj_t, bpr, nullptr, nullptr, nullptr, nullptr, nullptr, a_out);
}

// Round 9
// 202.783 us; speedup vs baseline: 1.1002x; 1.1002x over previous
//
#include <hip/hip_runtime.h>
#include <cstddef>
#include <cstdint>

// GPT-style attention block on MI355X (gfx950), bf16-MFMA.
//   x:[B,N,NX] f32, c_attn_w:[NX,3NX] f32, c_attn_b, c_proj_w:[NX,NX], c_proj_b
//   outputs: a:[B,N,NX] f32, present:[2,B,H,N,hd] f32  (k then v)
// mask input (d_in[5]) ignored: causal mask applied analytically.
#define NX_ 1024
#define NH_ 16
#define HD_ 64
#define B_  2
#define N_  2048
#define M_  (B_ * N_)   // 4096

typedef __attribute__((ext_vector_type(8))) short bf16x8;   // 8 bf16 (4 VGPR)
typedef __attribute__((ext_vector_type(4))) float f32x4;

// fp32 -> bf16 round-to-nearest-even (cold paths)
__device__ __forceinline__ unsigned short f2bf(float f) {
    union { float f; unsigned u; } v; v.f = f;
    return (unsigned short)((v.u + 0x7FFFu + ((v.u >> 16) & 1u)) >> 16);
}
__device__ __forceinline__ unsigned pk2bf(float a, float b) {
    return (unsigned)f2bf(a) | ((unsigned)f2bf(b) << 16);
}
// hot-path pack: round-half-up + v_perm byte select (3 VALU ops)
__device__ __forceinline__ unsigned pkrnd(float a, float b) {
    union { float f; unsigned u; } ua, ub; ua.f = a; ub.f = b;
    return __builtin_amdgcn_perm(ub.u + 0x8000u, ua.u + 0x8000u, 0x07060302u);
}
// bare v_exp_f32 (2^x), bypasses libm fixup; flushes to 0 for very negative x
__device__ __forceinline__ float exp2_hw(float x) {
    float r;
    asm("v_exp_f32 %0, %1" : "=v"(r) : "v"(x));
    return r;
}

// async global->LDS, 16B per lane; LDS dest = wave-uniform base + lane*16
__device__ __forceinline__ void gload_lds16(const void* g, void* l) {
    __builtin_amdgcn_global_load_lds(
        (const __attribute__((address_space(1))) unsigned int*)g,
        (__attribute__((address_space(3))) unsigned int*)l, 16, 0, 0);
}

// ---------------------------------------------------------------------------
// Fused pre-pass (one launch): bid<2048: x f32->bf16; then wqkv / wproj
// f32 -> bf16 TRANSPOSED ([ncols][1024]) via 32x32 LDS tiles.
__global__ __launch_bounds__(256)
void pre_pass(const float* __restrict__ x, unsigned short* __restrict__ xb,
              const float* __restrict__ wqkv, unsigned short* __restrict__ wqkv_t,
              const float* __restrict__ wpr, unsigned short* __restrict__ wproj_t)
{
    const int bid = blockIdx.x, t = threadIdx.x;
    if (bid < 2048) {
        const size_t i = ((size_t)bid * 256 + t) * 8;
        const float4 a = *(const float4*)(x + i);
        const float4 b = *(const float4*)(x + i + 4);
        uint4 o;
        o.x = pk2bf(a.x, a.y); o.y = pk2bf(a.z, a.w);
        o.z = pk2bf(b.x, b.y); o.w = pk2bf(b.z, b.w);
        *(uint4*)(xb + i) = o;
        return;
    }
    __shared__ unsigned short tile[32][40];
    const float* W; unsigned short* Wt; int ncols, n0, k0;
    if (bid < 2048 + 3072) {
        const int b2 = bid - 2048;
        W = wqkv; Wt = wqkv_t; ncols = 3072; n0 = (b2 % 96) * 32; k0 = (b2 / 96) * 32;
    } else {
        const int b3 = bid - 5120;
        W = wpr; Wt = wproj_t; ncols = 1024; n0 = (b3 & 31) * 32; k0 = (b3 >> 5) * 32;
    }
    const int r = t >> 3, c4 = (t & 7) * 4;
    const float4 v = *(const float4*)(W + (size_t)(k0 + r) * ncols + n0 + c4);
    tile[r][c4 + 0] = f2bf(v.x); tile[r][c4 + 1] = f2bf(v.y);
    tile[r][c4 + 2] = f2bf(v.z); tile[r][c4 + 3] = f2bf(v.w);
    __syncthreads();
    uint2 o;
    o.x = (unsigned)tile[c4 + 0][r] | ((unsigned)tile[c4 + 1][r] << 16);
    o.y = (unsigned)tile[c4 + 2][r] | ((unsigned)tile[c4 + 3][r] << 16);
    *(uint2*)(Wt + (size_t)(n0 + r) * 1024 + k0 + c4) = o;
}

// ---------------------------------------------------------------------------
// bf16 GEMM (r6-verified 2-phase loop): out = A[M,1024] @ Wt[NOUT,1024]^T + bias.
// BM=128, BN template (128 qkv / 64 proj), BK=32, 4 waves, dbuf LDS,
// global_load_lds staging with pre-swizzled global source.
// XCD mapping: bijective 2D patch per XCD (8 m-panels x JPX j-panels):
// concurrent L2 footprint 2MB A + (JPX*BN*2KB) W (qkv: 5MB vs 7MB linear).
// MODE 0 (qkv, BN=128): scatter epilogue -> q_bf (scaled), pk+k_bf, pv+v_t.
// MODE 1 (proj, BN=64): plain f32 out; grid 512 = 2 blocks/CU (was 1 -> the
// only GEMM with zero cross-block latency hiding; this is the occupancy fix).
// Bank-conflict counter note: ~3.1M/dispatch is structural gload_lds DMA
// serialization (8 cyc/instr), NOT read conflicts - benign, do not chase.
template<int NOUT, int MODE, int BN, int JPX, int OCC>
__global__ __launch_bounds__(256, OCC)
void gemm_mfma(const unsigned short* __restrict__ Ab, const unsigned short* __restrict__ Wt,
               const float* __restrict__ bias,
               float* __restrict__ o_pk, float* __restrict__ o_pv,
               unsigned short* __restrict__ o_q, unsigned short* __restrict__ o_k,
               unsigned short* __restrict__ o_vt, float* __restrict__ o_f)
{
    constexpr int NT = BN / 32;                 // n-tiles per wave
    __shared__ __align__(16) unsigned short As[2][128 * 32];
    __shared__ __align__(16) unsigned short Bs[2][BN * 32];
    const int t = threadIdx.x, l = t & 63;
    const int g = l >> 4, q15 = l & 15;
    const int w = t >> 6, wm = w >> 1, wn = w & 1;

    // bijective 2D XCD patch: 8 m-panels x JPX j-panels per XCD
    const int xcd = (int)blockIdx.x & 7, i = (int)blockIdx.x >> 3;
    const int mpanel = (xcd >> 1) * 8 + i / JPX;
    const int jpanel = (xcd & 1) * JPX + i % JPX;
    const int m0 = mpanel * 128, j0 = jpanel * BN;

    f32x4 acc[4][NT];
#pragma unroll
    for (int ii = 0; ii < 4; ii++)
#pragma unroll
        for (int jj = 0; jj < NT; jj++) { acc[ii][jj][0]=0.f; acc[ii][jj][1]=0.f; acc[ii][jj][2]=0.f; acc[ii][jj][3]=0.f; }

    const int srowA0 = (w * 2 + 0) * 16 + (l >> 2);
    const int srowA1 = (w * 2 + 1) * 16 + (l >> 2);
    const int kctA0 = ((l & 3) ^ (srowA0 & 3) ^ ((srowA0 >> 2) & 3)) & 3;
    const int kctA1 = ((l & 3) ^ (srowA1 & 3) ^ ((srowA1 >> 2) & 3)) & 3;
    const int srowB  = w * 16 + (l >> 2);       // used when BN==64
    const int kctB  = ((l & 3) ^ (srowB & 3) ^ ((srowB >> 2) & 3)) & 3;

#define STAGE(BUF, K0)                                                          \
    do {                                                                        \
        gload_lds16(Ab + (size_t)(m0 + srowA0) * 1024 + (K0) + kctA0 * 8,       \
                    &As[BUF][(w * 2 + 0) * 512]);                               \
        gload_lds16(Ab + (size_t)(m0 + srowA1) * 1024 + (K0) + kctA1 * 8,       \
                    &As[BUF][(w * 2 + 1) * 512]);                               \
        if (BN == 128) {                                                        \
            gload_lds16(Wt + (size_t)(j0 + srowA0) * 1024 + (K0) + kctA0 * 8,   \
                        &Bs[BUF][(w * 2 + 0) * 512]);                           \
            gload_lds16(Wt + (size_t)(j0 + srowA1) * 1024 + (K0) + kctA1 * 8,   \
                        &Bs[BUF][(w * 2 + 1) * 512]);                           \
        } else {                                                                \
            gload_lds16(Wt + (size_t)(j0 + srowB) * 1024 + (K0) + kctB * 8,     \
                        &Bs[BUF][w * 512]);                                     \
        }                                                                       \
    } while (0)

    STAGE(0, 0);
    __syncthreads();

    for (int kk = 0; kk < 32; ++kk) {
        const int buf = kk & 1;
        if (kk + 1 < 32) STAGE(buf ^ 1, (kk + 1) * 32);

        bf16x8 af[4], bfv[NT];
#pragma unroll
        for (int mt = 0; mt < 4; mt++) {
            const int m = wm * 64 + mt * 16 + q15;
            af[mt] = *(const bf16x8*)&As[buf][m * 32 + ((g ^ (m & 3) ^ ((m >> 2) & 3)) & 3) * 8];
        }
#pragma unroll
        for (int nt = 0; nt < NT; nt++) {
            const int n = wn * (BN / 2) + nt * 16 + q15;
            bfv[nt] = *(const bf16x8*)&Bs[buf][n * 32 + ((g ^ (n & 3) ^ ((n >> 2) & 3)) & 3) * 8];
        }
#pragma unroll
        for (int mt = 0; mt < 4; mt++)
#pragma unroll
            for (int nt = 0; nt < NT; nt++)
                acc[mt][nt] = __builtin_amdgcn_mfma_f32_16x16x32_bf16(af[mt], bfv[nt], acc[mt][nt], 0, 0, 0);

        __syncthreads();
    }

#pragma unroll
    for (int nt = 0; nt < NT; nt++) {
        const int ncol = wn * (BN / 2) + nt * 16 + q15;
        const int jc = j0 + ncol;
        const float bz = bias[jc];
        const int sec = jc >> 10, jl = jc & 1023, hh = jl >> 6, dd = jl & 63;
#pragma unroll
        for (int mt = 0; mt < 4; mt++) {
#pragma unroll
            for (int r = 0; r < 4; r++) {
                const int m = m0 + wm * 64 + mt * 16 + g * 4 + r;
                const float val = acc[mt][nt][r] + bz;
                if (MODE == 1) {
                    o_f[(size_t)m * NOUT + jc] = val;
                } else {
                    const int bb = m >> 11, nn = m & 2047;
                    const int bhh = bb * NH_ + hh;
                    const size_t idx = ((size_t)bhh * N_ + nn) * HD_ + dd;
                    if (sec == 0)      o_q[idx] = f2bf(val * 0.18033688f); // 1/8 * log2(e)
                    else if (sec == 1) { o_pk[idx] = val; o_k[idx] = f2bf(val); }
                    else               { o_pv[idx] = val;
                                         o_vt[((size_t)bhh * HD_ + dd) * N_ + nn] = f2bf(val); }
                }
            }
        }
    }
#undef STAGE
}

// ---------------------------------------------------------------------------
// Flash attention, bf16 MFMA, fixed-max softmax. QBLK=128 (8 waves x 16 rows).
// Swapped QK^T (S^T = K.Q^T) -> lane-local P; PV as O^T = V^T.P.
// (r6-verified version, unchanged.)
__global__ __launch_bounds__(512, 2)
void attn_mfma(const unsigned short* __restrict__ q_bf,
               const unsigned short* __restrict__ k_bf,
               const unsigned short* __restrict__ v_t,
               unsigned short* __restrict__ a_pre)
{
    __shared__ __align__(16) unsigned short Ks[2][64 * 64];
    __shared__ __align__(16) unsigned short Vt[2][64 * 64];
    __shared__ __align__(16) unsigned short Ps[128 * 64];

    const int t = threadIdx.x, l = t & 63, w = t >> 6;   // w: 0..7
    const int g = l >> 4, q15 = l & 15;

    const int bid = (int)blockIdx.x;
    const int x = bid & 7, r = bid >> 3;                 // r: 0..63
    const int bh = x * 4 + (r & 3);
    const int j = r >> 2;                                // 0..15
    const int qt = (j < 8) ? (15 - j) : (j - 8);
    const int b = bh >> 4, h = bh & 15;

    const unsigned short* kb  = k_bf + (size_t)bh * N_ * HD_;
    const unsigned short* vtb = v_t  + (size_t)bh * HD_ * N_;

    const int qrow = w * 16 + q15;                       // 0..127
    const int qg = qt * 128 + qrow;                      // global q row
    const unsigned short* qp = q_bf + ((size_t)bh * N_ + qg) * HD_ + g * 8;
    const bf16x8 qf0 = *(const bf16x8*)(qp);
    const bf16x8 qf1 = *(const bf16x8*)(qp + 32);

    const int sr = t >> 3, s8 = t & 7;
    uint4 stgK, stgV;

#define ISSUE(KT)                                                               \
    do {                                                                        \
        stgK = *(const uint4*)(kb + ((size_t)((KT) * 64 + sr)) * HD_ + s8 * 8); \
        stgV = *(const uint4*)(vtb + (size_t)sr * N_ + (KT) * 64 + s8 * 8);     \
    } while (0)

#define COMMIT(BUF)                                                             \
    do {                                                                        \
        *(uint4*)&Ks[BUF][sr * 64 + ((s8 ^ (sr & 7)) & 7) * 8] = stgK;          \
        *(uint4*)&Vt[BUF][sr * 64 + ((s8 ^ (sr & 7)) & 7) * 8] = stgV;          \
    } while (0)

    ISSUE(0); COMMIT(0);
    __syncthreads();

    float l_i = 0.f;
    f32x4 oacc[4];
#pragma unroll
    for (int i = 0; i < 4; i++) { oacc[i][0]=0.f; oacc[i][1]=0.f; oacc[i][2]=0.f; oacc[i][3]=0.f; }

    int cur = 0;
    char* const prow = (char*)Ps + qrow * 128;
    const int psw = (qrow & 7) << 4;
    const int ktmax = 2 * qt + 1;

    for (int kt = 0; kt <= ktmax; kt++) {
        const bool more = (kt < ktmax);
        if (more) ISSUE(kt + 1);                  // T14: issue next tile early

        // ---- S^T = K . Q^T
        f32x4 sacc[4];
#pragma unroll
        for (int i = 0; i < 4; i++) { sacc[i][0]=0.f; sacc[i][1]=0.f; sacc[i][2]=0.f; sacc[i][3]=0.f; }
        __builtin_amdgcn_s_setprio(1);
#pragma unroll
        for (int kt4 = 0; kt4 < 4; kt4++) {
            const int row = kt4 * 16 + q15;
            const bf16x8 kf0 = *(const bf16x8*)&Ks[cur][row * 64 + ((g ^ (row & 7)) & 7) * 8];
            sacc[kt4] = __builtin_amdgcn_mfma_f32_16x16x32_bf16(kf0, qf0, sacc[kt4], 0, 0, 0);
            const bf16x8 kf1 = *(const bf16x8*)&Ks[cur][row * 64 + (((g + 4) ^ (row & 7)) & 7) * 8];
            sacc[kt4] = __builtin_amdgcn_mfma_f32_16x16x32_bf16(kf1, qf1, sacc[kt4], 0, 0, 0);
        }
        __builtin_amdgcn_s_setprio(0);

        // ---- P = exp2(S), per-thread partial sum, bf16 pack into private Ps rows
        float pe[16];
        if (kt >= 2 * qt) {   // diagonal region: mask global kc > global q
#pragma unroll
            for (int kt4 = 0; kt4 < 4; kt4++)
#pragma unroll
                for (int rr = 0; rr < 4; rr++) {
                    const int kcg = kt * 64 + kt4 * 16 + g * 4 + rr;
                    const float s = (kcg > qg) ? -1.0e30f : sacc[kt4][rr];
                    pe[kt4 * 4 + rr] = exp2_hw(s);
                }
        } else {
#pragma unroll
            for (int kt4 = 0; kt4 < 4; kt4++)
#pragma unroll
                for (int rr = 0; rr < 4; rr++) pe[kt4 * 4 + rr] = exp2_hw(sacc[kt4][rr]);
        }
        {   // tree-sum of the 16 partials (depth 4)
            float s8v[8];
#pragma unroll
            for (int i = 0; i < 8; i++) s8v[i] = pe[2 * i] + pe[2 * i + 1];
            const float s0 = (s8v[0] + s8v[1]) + (s8v[2] + s8v[3]);
            const float s1 = (s8v[4] + s8v[5]) + (s8v[6] + s8v[7]);
            l_i += s0 + s1;
        }
#pragma unroll
        for (int kt4 = 0; kt4 < 4; kt4++) {
            uint2 w2;
            w2.x = pkrnd(pe[kt4 * 4 + 0], pe[kt4 * 4 + 1]);
            w2.y = pkrnd(pe[kt4 * 4 + 2], pe[kt4 * 4 + 3]);
            *(uint2*)(prow + ((kt4 * 32 + g * 8) ^ psw)) = w2;
        }

        // ---- O^T += V^T . P
        {
            const bf16x8 pf0 = *(const bf16x8*)(prow + ((g * 16) ^ psw));
            const bf16x8 pf1 = *(const bf16x8*)(prow + (((g + 4) * 16) ^ psw));
            __builtin_amdgcn_s_setprio(1);
#pragma unroll
            for (int dt = 0; dt < 4; dt++) {
                const int vrow = dt * 16 + q15;
                const bf16x8 vf = *(const bf16x8*)&Vt[cur][vrow * 64 + ((g ^ (vrow & 7)) & 7) * 8];
                oacc[dt] = __builtin_amdgcn_mfma_f32_16x16x32_bf16(vf, pf0, oacc[dt], 0, 0, 0);
            }
#pragma unroll
            for (int dt = 0; dt < 4; dt++) {
                const int vrow = dt * 16 + q15;
                const bf16x8 vf = *(const bf16x8*)&Vt[cur][vrow * 64 + (((g + 4) ^ (vrow & 7)) & 7) * 8];
                oacc[dt] = __builtin_amdgcn_mfma_f32_16x16x32_bf16(vf, pf1, oacc[dt], 0, 0, 0);
            }
            __builtin_amdgcn_s_setprio(0);
        }

        if (more) COMMIT(cur ^ 1);                // write next tile late
        __syncthreads();
        cur ^= 1;
    }

    // deferred cross-lane l reduce (lanes l, l^16, l^32 share the q-column)
    float lt = l_i;
    lt += __shfl_xor(lt, 16);
    lt += __shfl_xor(lt, 32);
    const float inv = 1.0f / lt;

    unsigned short* ap2 = a_pre + ((size_t)(b * N_ + qg)) * NX_ + h * 64;
#pragma unroll
    for (int dt = 0; dt < 4; dt++) {
#pragma unroll
        for (int j2 = 0; j2 < 2; j2++) {
            const int d = dt * 16 + g * 4 + j2 * 2;
            *(unsigned*)(ap2 + d) = pkrnd(oacc[dt][j2 * 2] * inv, oacc[dt][j2 * 2 + 1] * inv);
        }
    }
#undef ISSUE
#undef COMMIT
}

// ---------------------------------------------------------------------------
extern "C" void kernel_launch(void* const* d_in, const int* in_sizes, int n_in,
                              void* d_out, int out_size, void* d_ws, size_t ws_size,
                              hipStream_t stream)
{
    (void)in_sizes; (void)n_in; (void)out_size; (void)ws_size;
    const float* x    = (const float*)d_in[0];
    const float* wqkv = (const float*)d_in[1];
    const float* bqkv = (const float*)d_in[2];
    const float* wpr  = (const float*)d_in[3];
    const float* bpr  = (const float*)d_in[4];
    // d_in[5] (mask) ignored: causal mask applied analytically.

    float* out   = (float*)d_out;
    float* a_out = out;                                  // [B,N,NX] f32
    float* pk    = out + (size_t)M_ * NX_;               // present[0]: k [B,H,N,hd]
    float* pv    = pk + (size_t)B_ * NH_ * N_ * HD_;     // present[1]: v

    // workspace (40 MB): bf16 x / q / k / v^T / transposed weights.
    // a_pre aliases xb: xb fully consumed by qkv GEMM before attn writes.
    const size_t SEG = (size_t)M_ * NX_;                 // 4M elems
    unsigned short* xb      = (unsigned short*)d_ws;     // [4096][1024]
    unsigned short* q_bf    = xb + SEG;                  // [bh][n][d]
    unsigned short* k_bf    = q_bf + SEG;                // [bh][n][d]
    unsigned short* v_t     = k_bf + SEG;                // [bh][d][n]
    unsigned short* wqkv_t  = v_t + SEG;                 // [3072][1024]
    unsigned short* wproj_t = wqkv_t + (size_t)3 * NX_ * NX_;  // [1024][1024]
    unsigned short* a_pre   = xb;                        // alias (see above)

    pre_pass<<<2048 + 3072 + 1024, 256, 0, stream>>>(x, xb, wqkv, wqkv_t, wpr, wproj_t);

    gemm_mfma<3 * NX_, 0, 128, 12, 3><<<768, 256, 0, stream>>>(
        xb, wqkv_t, bqkv, pk, pv, q_bf, k_bf, v_t, nullptr);
    attn_mfma<<<512, 512, 0, stream>>>(q_bf, k_bf, v_t, a_pre);
    gemm_mfma<NX_, 1, 64, 8, 2><<<512, 256, 0, stream>>>(
        a_pre, wproj_t, bpr, nullptr, nullptr, nullptr, nullptr, nullptr, a_out);
}